// Round 9
// baseline (125.496 us; speedup 1.0000x reference)
//
#include <hip/hip_runtime.h>

#define DEVINL __device__ __forceinline__

typedef __attribute__((ext_vector_type(8))) short bf16x8;
typedef __attribute__((ext_vector_type(8))) unsigned short u16x8;
typedef __attribute__((ext_vector_type(4))) float f32x4;

constexpr int BUCKET = 96;  // max neighbors per atom (Poisson(16): P(>=96) ~ 0)

// ===========================================================================
// Compile-time math: even-parity triples (l1,l2,l3) and scalar A per triple.
// (T_p[(l1,l2,l3),m] = A * Y_{l3,m}(u_p); odd-parity A == 0.)  Verified R3/R4.
// ===========================================================================
constexpr int LMAX = 4;

struct Triples { int n; int l1[80], l2[80], l3[80]; };
constexpr Triples make_triples() {
  Triples T{}; T.n = 0;
  for (int a = 0; a <= LMAX; ++a)
    for (int b = 0; b <= LMAX; ++b)
      for (int c = 0; c <= LMAX; ++c) {
        int lo = a > b ? a - b : b - a;
        if (c < lo || c > a + b) continue;
        T.l1[T.n] = a; T.l2[T.n] = b; T.l3[T.n] = c; ++T.n;
      }
  return T;
}
constexpr Triples TRI = make_triples();
static_assert(TRI.n == 65, "triples");

struct ETriT { int n; signed char l1[48], l2[48], l3[48]; };
constexpr ETriT make_etri() {
  ETriT E{}; E.n = 0;
  for (int t = 0; t < TRI.n; ++t)
    if (((TRI.l1[t] + TRI.l2[t] + TRI.l3[t]) & 1) == 0) {
      E.l1[E.n] = (signed char)TRI.l1[t];
      E.l2[E.n] = (signed char)TRI.l2[t];
      E.l3[E.n] = (signed char)TRI.l3[t];
      ++E.n;
    }
  return E;
}
constexpr ETriT ETRI = make_etri();
static_assert(ETRI.n == 42, "even triples");

constexpr double FT[14] = {1., 1., 2., 6., 24., 120., 720., 5040., 40320.,
                           362880., 3628800., 39916800., 479001600., 6227020800.};

constexpr double csqrt(double x) {
  if (x <= 0.0) return 0.0;
  double y = 1.0;
  while (y * y < x) y *= 2.0;
  for (int i = 0; i < 30; ++i) y = 0.5 * (y + x / y);
  return y;
}

constexpr double cg_complex(int l1, int m1, int l2, int m2, int l3, int m3) {
  if (m1 + m2 != m3) return 0.0;
  double pref = csqrt((2.0 * l3 + 1.0) * FT[l1 + l2 - l3] * FT[l1 - l2 + l3] *
                      FT[-l1 + l2 + l3] / FT[l1 + l2 + l3 + 1]);
  pref *= csqrt(FT[l1 + m1] * FT[l1 - m1] * FT[l2 + m2] * FT[l2 - m2] *
                FT[l3 + m3] * FT[l3 - m3]);
  double s = 0.0;
  for (int k = 0; k <= l1 + l2 - l3; ++k) {
    int d3 = l1 - m1 - k, d4 = l2 + m2 - k, d5 = l3 - l2 + m1 + k, d6 = l3 - l1 - m2 + k;
    if (d3 < 0 || d4 < 0 || d5 < 0 || d6 < 0) continue;
    double den = FT[k] * FT[l1 + l2 - l3 - k] * FT[d3] * FT[d4] * FT[d5] * FT[d6];
    s += ((k & 1) ? -1.0 : 1.0) / den;
  }
  return pref * s;
}

struct CURow { int n; int m[2]; double re[2], im[2]; };
constexpr CURow cu_row(int l, int a) {
  CURow u{}; int ma = a - l;
  const double RS2 = 0.70710678118654752440;
  if (ma == 0) { u.n = 1; u.m[0] = 0; u.re[0] = 1.0; u.im[0] = 0.0; }
  else if (ma > 0) {
    u.n = 2;
    u.m[0] = ma;  u.re[0] = ((ma & 1) ? -RS2 : RS2); u.im[0] = 0.0;
    u.m[1] = -ma; u.re[1] = RS2;                     u.im[1] = 0.0;
  } else {
    int mm = -ma; u.n = 2;
    u.m[0] = -mm; u.re[0] = 0.0; u.im[0] = RS2;
    u.m[1] =  mm; u.re[1] = 0.0; u.im[1] = ((mm & 1) ? RS2 : -RS2);
  }
  return u;
}

constexpr double real_cg_entry(int l1, int a, int l2, int b, int l3, int c) {
  CURow u1 = cu_row(l1, a), u2 = cu_row(l2, b), u3 = cu_row(l3, c);
  double sre = 0.0, sim = 0.0;
  for (int x = 0; x < u1.n; ++x)
    for (int y = 0; y < u2.n; ++y)
      for (int z = 0; z < u3.n; ++z) {
        int m1 = u1.m[x], m2 = u2.m[y], m3 = u3.m[z];
        if (m1 + m2 != m3) continue;
        double cg = cg_complex(l1, m1, l2, m2, l3, m3);
        if (cg == 0.0) continue;
        double are = u1.re[x], aim = u1.im[x], bre = u2.re[y], bim = u2.im[y];
        double pre = are * bre - aim * bim, pim = are * bim + aim * bre;
        double cre = u3.re[z], cim = -u3.im[z];
        sre += (pre * cre - pim * cim) * cg;
        sim += (pre * cim + pim * cre) * cg;
      }
  return ((l1 + l2 + l3) & 1) ? sim : sre;
}

struct Y25D { double y[25]; };
constexpr Y25D csh25(double x, double y, double z) {
  Y25D Y{};
  double x2 = x * x, y2 = y * y, z2 = z * z;
  Y.y[0] = 0.28209479177387814;
  Y.y[1] = 0.4886025119029199 * y;
  Y.y[2] = 0.4886025119029199 * z;
  Y.y[3] = 0.4886025119029199 * x;
  Y.y[4] = 1.0925484305920792 * x * y;
  Y.y[5] = 1.0925484305920792 * y * z;
  Y.y[6] = 0.31539156525252005 * (3.0 * z2 - 1.0);
  Y.y[7] = 1.0925484305920792 * x * z;
  Y.y[8] = 0.5462742152960396 * (x2 - y2);
  Y.y[9] = 0.5900435899266435 * y * (3.0 * x2 - y2);
  Y.y[10] = 2.890611442640554 * x * y * z;
  Y.y[11] = 0.4570457994644658 * y * (5.0 * z2 - 1.0);
  Y.y[12] = 0.3731763325901154 * z * (5.0 * z2 - 3.0);
  Y.y[13] = 0.4570457994644658 * x * (5.0 * z2 - 1.0);
  Y.y[14] = 1.445305721320277 * z * (x2 - y2);
  Y.y[15] = 0.5900435899266435 * x * (x2 - 3.0 * y2);
  Y.y[16] = 2.5033429417967046 * x * y * (x2 - y2);
  Y.y[17] = 1.7701307697799304 * y * z * (3.0 * x2 - y2);
  Y.y[18] = 0.9461746957575601 * x * y * (7.0 * z2 - 1.0);
  Y.y[19] = 0.6690465435572892 * y * z * (7.0 * z2 - 3.0);
  Y.y[20] = 0.10578554691520431 * (35.0 * z2 * z2 - 30.0 * z2 + 3.0);
  Y.y[21] = 0.6690465435572892 * x * z * (7.0 * z2 - 3.0);
  Y.y[22] = 0.47308734787878004 * (x2 - y2) * (7.0 * z2 - 1.0);
  Y.y[23] = 1.7701307697799304 * x * z * (x2 - 3.0 * y2);
  Y.y[24] = 0.6258357354491761 * (x2 * x2 - 6.0 * x2 * y2 + y2 * y2);
  return Y;
}

constexpr double compute_A_even(int e) {
  int l1 = ETRI.l1[e], l2 = ETRI.l2[e], l3 = ETRI.l3[e];
  double ux = 0.437, uy = -0.602, uz = 0.668;
  double n = csqrt(ux * ux + uy * uy + uz * uz);
  Y25D Y = csh25(ux / n, uy / n, uz / n);
  int c0 = 2 * l3;
  double den = Y.y[l3 * l3 + c0];
  double num = 0.0;
  for (int a = 0; a < 2 * l1 + 1; ++a)
    for (int b = 0; b < 2 * l2 + 1; ++b) {
      double v = real_cg_entry(l1, a, l2, b, l3, c0);
      if (v != 0.0) num += v * Y.y[l1 * l1 + a] * Y.y[l2 * l2 + b];
    }
  return num / den;
}

template <int E> inline constexpr float A_of = (float)compute_A_even(E);
constexpr float AT42[42] = {
    A_of<0>,  A_of<1>,  A_of<2>,  A_of<3>,  A_of<4>,  A_of<5>,  A_of<6>,
    A_of<7>,  A_of<8>,  A_of<9>,  A_of<10>, A_of<11>, A_of<12>, A_of<13>,
    A_of<14>, A_of<15>, A_of<16>, A_of<17>, A_of<18>, A_of<19>, A_of<20>,
    A_of<21>, A_of<22>, A_of<23>, A_of<24>, A_of<25>, A_of<26>, A_of<27>,
    A_of<28>, A_of<29>, A_of<30>, A_of<31>, A_of<32>, A_of<33>, A_of<34>,
    A_of<35>, A_of<36>, A_of<37>, A_of<38>, A_of<39>, A_of<40>, A_of<41>};

// ===========================================================================
// Device helpers
// ===========================================================================
DEVINL unsigned short f2bf(float x) {
  unsigned u = __float_as_uint(x);
  u += 0x7FFFu + ((u >> 16) & 1u);
  return (unsigned short)(u >> 16);
}
DEVINL float bf2f(unsigned short b) { return __uint_as_float((unsigned)b << 16); }
DEVINL unsigned short f2h(float x) {
  return __builtin_bit_cast(unsigned short, (_Float16)x);
}
DEVINL float h2f(unsigned short h) {
  return (float)__builtin_bit_cast(_Float16, h);
}

DEVINL void sh25(float x, float y, float z, float* Y) {
  float x2 = x * x, y2 = y * y, z2 = z * z;
  Y[0] = 0.28209479177387814f;
  Y[1] = 0.4886025119029199f * y;
  Y[2] = 0.4886025119029199f * z;
  Y[3] = 0.4886025119029199f * x;
  Y[4] = 1.0925484305920792f * x * y;
  Y[5] = 1.0925484305920792f * y * z;
  Y[6] = 0.31539156525252005f * (3.0f * z2 - 1.0f);
  Y[7] = 1.0925484305920792f * x * z;
  Y[8] = 0.5462742152960396f * (x2 - y2);
  Y[9] = 0.5900435899266435f * y * (3.0f * x2 - y2);
  Y[10] = 2.890611442640554f * x * y * z;
  Y[11] = 0.4570457994644658f * y * (5.0f * z2 - 1.0f);
  Y[12] = 0.3731763325901154f * z * (5.0f * z2 - 3.0f);
  Y[13] = 0.4570457994644658f * x * (5.0f * z2 - 1.0f);
  Y[14] = 1.445305721320277f * z * (x2 - y2);
  Y[15] = 0.5900435899266435f * x * (x2 - 3.0f * y2);
  Y[16] = 2.5033429417967046f * x * y * (x2 - y2);
  Y[17] = 1.7701307697799304f * y * z * (3.0f * x2 - y2);
  Y[18] = 0.9461746957575601f * x * y * (7.0f * z2 - 1.0f);
  Y[19] = 0.6690465435572892f * y * z * (7.0f * z2 - 3.0f);
  Y[20] = 0.10578554691520431f * (35.0f * z2 * z2 - 30.0f * z2 + 3.0f);
  Y[21] = 0.6690465435572892f * x * z * (7.0f * z2 - 3.0f);
  Y[22] = 0.47308734787878004f * (x2 - y2) * (7.0f * z2 - 1.0f);
  Y[23] = 1.7701307697799304f * x * z * (x2 - 3.0f * y2);
  Y[24] = 0.6258357354491761f * (x2 * x2 - 6.0f * x2 * y2 + y2 * y2);
}

// ===========================================================================
// ktw: W -> bf16 WT [l*64+g][c]; block 159 also zeroes counts[]
// ===========================================================================
__global__ void ktw(const float* __restrict__ W1, const float* __restrict__ W2,
                    unsigned short* __restrict__ WT, int* __restrict__ counts, int A) {
  int idx = blockIdx.x * 256 + threadIdx.x;
  if (blockIdx.x == 159) {
    for (int i = threadIdx.x; i < A; i += 256) counts[i] = 0;
  }
  if (idx >= 40960) return;
  int c = idx & 63, g = (idx >> 6) & 63, l = idx >> 12;
  const float* W = (l < 5) ? (W1 + (size_t)l * 4096) : (W2 + (size_t)(l - 5) * 4096);
  WT[idx] = f2bf(W[c * 64 + g]);
}

// ===========================================================================
// kA: blocks [0, P/64): 64-pair MFMA tile, ALL 64 g via 4-chunk loop
//     (radial staged ONCE per pair; A-frags reused across chunks).
//     blocks [P/64, ..): histogram + bucket scatter.
// G record (16 B per (p,f)): [5 bf16 G(l3) | 3 fp16 unit-dir] -> k3 needs ONE
// dwordx4 per pair and no disp gather / sqrt.
// ===========================================================================
__global__ __launch_bounds__(256) void kA(const int* __restrict__ Z,
                                          const int* __restrict__ nbr,
                                          const float* __restrict__ disp,
                                          const float* __restrict__ se,
                                          const unsigned short* __restrict__ WT,
                                          const float* __restrict__ b1,
                                          const float* __restrict__ b2,
                                          unsigned short* __restrict__ G,
                                          int* __restrict__ counts,
                                          int* __restrict__ plist2,
                                          int P) {
  const int nGemm = P / 64;
  const int t = threadIdx.x;

  if ((int)blockIdx.x >= nGemm) {
    int p = ((int)blockIdx.x - nGemm) * 256 + t;
    if (p < P) {
      int a = nbr[p];
      int rank = atomicAdd(&counts[a], 1);
      if (rank < BUCKET) plist2[a * BUCKET + rank] = p;
    }
    return;
  }

  __shared__ alignas(16) unsigned short rad[64 * 72];  // [pair][c] bf16
  __shared__ unsigned short dird[64 * 3];              // fp16 unit dir per pair
  const int p0 = (int)blockIdx.x * 64;

  // ---- stage radial once: 4 threads per pair, 16 c each ----
  {
    int pl = t >> 2, qt = t & 3;
    int p = p0 + pl;
    int zj = Z[nbr[P + p]];
    float dx = disp[3 * p], dy = disp[3 * p + 1], dz = disp[3 * p + 2];
    float r = sqrtf(dx * dx + dy * dy + dz * dz + 1e-12f);
    float env = 0.5f * (__cosf(3.14159265358979f * fminf(r * 0.2f, 1.0f)) + 1.0f);
    const float delta = 5.0f / 63.0f;
    const float w = 0.5f / (delta * delta);
    if (qt == 0) {
      float inv = 1.0f / r;
      dird[pl * 3 + 0] = f2h(dx * inv);
      dird[pl * 3 + 1] = f2h(dy * inv);
      dird[pl * 3 + 2] = f2h(dz * inv);
    }
    int c0 = qt * 16;
    const float4* s4 = (const float4*)(se + (size_t)zj * 64 + c0);
    unsigned* radw = (unsigned*)rad;
#pragma unroll
    for (int i = 0; i < 4; ++i) {
      float4 s = s4[i];
      float d0 = r - (float)(c0 + 4 * i + 0) * delta;
      float d1 = r - (float)(c0 + 4 * i + 1) * delta;
      float d2 = r - (float)(c0 + 4 * i + 2) * delta;
      float d3 = r - (float)(c0 + 4 * i + 3) * delta;
      float v0 = __expf(-w * d0 * d0) * env * s.x;
      float v1 = __expf(-w * d1 * d1) * env * s.y;
      float v2 = __expf(-w * d2 * d2) * env * s.z;
      float v3 = __expf(-w * d3 * d3) * env * s.w;
      radw[pl * 36 + qt * 8 + 2 * i]     = (unsigned)f2bf(v0) | ((unsigned)f2bf(v1) << 16);
      radw[pl * 36 + qt * 8 + 2 * i + 1] = (unsigned)f2bf(v2) | ((unsigned)f2bf(v3) << 16);
    }
  }
  __syncthreads();

  const int lane = t & 63, wv = t >> 6;
  const int n = lane & 15, quad = lane >> 4;
  const float invY0 = 3.5449077018110318f;

  // A-frags: wave's m-rows are wv*16..wv*16+15; load once, reuse for all g.
  const int row = wv * 16 + n;
  bf16x8 A0 = *(const bf16x8*)(rad + row * 72 + quad * 8);
  bf16x8 A1 = *(const bf16x8*)(rad + row * 72 + 32 + quad * 8);

  // dir halves for the 4 pairs this lane stores (p = wv*16 + quad*4 + r)
  unsigned short dh[4][3];
#pragma unroll
  for (int r = 0; r < 4; ++r) {
    int lp = wv * 16 + quad * 4 + r;
    dh[r][0] = dird[lp * 3 + 0];
    dh[r][1] = dird[lp * 3 + 1];
    dh[r][2] = dird[lp * 3 + 2];
  }

#pragma unroll 1
  for (int ch = 0; ch < 4; ++ch) {
    const int g = ch * 16 + n;

    bf16x8 B[10][2];
#pragma unroll
    for (int l = 0; l < 10; ++l)
#pragma unroll
      for (int kk = 0; kk < 2; ++kk)
        B[l][kk] = *(const bf16x8*)(WT + (((size_t)l * 64 + g) * 64 + kk * 32 + quad * 8));

    float bb1 = b1[g] * invY0, bb2 = b2[g] * invY0;

    f32x4 C[10];
#pragma unroll
    for (int l = 0; l < 10; ++l) C[l] = (f32x4){0.f, 0.f, 0.f, 0.f};
#pragma unroll
    for (int l = 0; l < 10; ++l) {
      C[l] = __builtin_amdgcn_mfma_f32_16x16x32_bf16(A0, B[l][0], C[l], 0, 0, 0);
      C[l] = __builtin_amdgcn_mfma_f32_16x16x32_bf16(A1, B[l][1], C[l], 0, 0, 0);
    }
#pragma unroll
    for (int r = 0; r < 4; ++r) { C[0][r] += bb1; C[5][r] += bb2; }

    f32x4 Gac[5];
#pragma unroll
    for (int l = 0; l < 5; ++l) Gac[l] = (f32x4){0.f, 0.f, 0.f, 0.f};
#pragma unroll
    for (int l1 = 0; l1 < 5; ++l1)
#pragma unroll
      for (int l2 = 0; l2 < 5; ++l2) {
        f32x4 pr = C[l1] * C[5 + l2];
#pragma unroll
        for (int e = 0; e < 42; ++e)
          if ((int)ETRI.l1[e] == l1 && (int)ETRI.l2[e] == l2)
            Gac[(int)ETRI.l3[e]] += AT42[e] * pr;
      }

    const int prow = p0 + wv * 16 + quad * 4;
#pragma unroll
    for (int r = 0; r < 4; ++r) {
      u16x8 pack;
      pack[0] = f2bf(Gac[0][r]); pack[1] = f2bf(Gac[1][r]);
      pack[2] = f2bf(Gac[2][r]); pack[3] = f2bf(Gac[3][r]);
      pack[4] = f2bf(Gac[4][r]);
      pack[5] = dh[r][0]; pack[6] = dh[r][1]; pack[7] = dh[r][2];
      *(u16x8*)(G + (size_t)(prow + r) * 512 + g * 8) = pack;
    }
  }
}

// ===========================================================================
// k3: ONE wave per atom (4 atoms/block), lane = f. No LDS reduce. Per pair:
// one dwordx4 of G (G values + fp16 unit dir) -> sh25 -> 29 fma. Prefetched.
// ===========================================================================
__global__ __launch_bounds__(256) void k3(const unsigned short* __restrict__ G,
                                          const int* __restrict__ Z,
                                          const float* __restrict__ se,
                                          const float* __restrict__ Wt,
                                          const float* __restrict__ bt,
                                          const int* __restrict__ counts,
                                          const int* __restrict__ plist2,
                                          float* __restrict__ out, int A) {
  const int wv = threadIdx.x >> 6, f = threadIdx.x & 63;
  const int atom = blockIdx.x * 4 + wv;
  if (atom >= A) return;

  float acc[25];
#pragma unroll
  for (int k = 0; k < 25; ++k) acc[k] = 0.f;

  int cnt = counts[atom];
  cnt = cnt < BUCKET ? cnt : BUCKET;
  const int* bucket = plist2 + (size_t)atom * BUCKET;

  u16x8 gv;
  if (cnt > 0) {
    int p = __builtin_amdgcn_readfirstlane(bucket[0]);
    gv = *(const u16x8*)(G + (size_t)p * 512 + f * 8);
  }
  for (int q = 0; q < cnt; ++q) {
    u16x8 gc = gv;
    if (q + 1 < cnt) {
      int p = __builtin_amdgcn_readfirstlane(bucket[q + 1]);
      gv = *(const u16x8*)(G + (size_t)p * 512 + f * 8);
    }
    float g0 = bf2f(gc[0]), g1 = bf2f(gc[1]), g2 = bf2f(gc[2]);
    float g3 = bf2f(gc[3]), g4 = bf2f(gc[4]);
    float ux = h2f(gc[5]), uy = h2f(gc[6]), uz = h2f(gc[7]);
    float Y[25];
    sh25(ux, uy, uz, Y);
    acc[0] = fmaf(Y[0], g0, acc[0]);
#pragma unroll
    for (int k = 1; k < 4; ++k)   acc[k] = fmaf(Y[k], g1, acc[k]);
#pragma unroll
    for (int k = 4; k < 9; ++k)   acc[k] = fmaf(Y[k], g2, acc[k]);
#pragma unroll
    for (int k = 9; k < 16; ++k)  acc[k] = fmaf(Y[k], g3, acc[k]);
#pragma unroll
    for (int k = 16; k < 25; ++k) acc[k] = fmaf(Y[k], g4, acc[k]);
  }

  // fused emb row: (se[Z[atom]] @ Wt + bt)[f]
  int z = Z[atom];
  float e = bt[f];
  for (int c = 0; c < 64; ++c)
    e = fmaf(se[(size_t)z * 64 + c], Wt[(size_t)c * 64 + f], e);

#pragma unroll
  for (int k = 0; k < 25; ++k)
    out[(size_t)atom * 1600 + (size_t)k * 64 + f] = fmaf(acc[k], e, (k == 0) ? e : 0.f);
}

// ===========================================================================
// Launch: 3 dispatches
// ===========================================================================
static inline size_t align256(size_t x) { return (x + 255) & ~(size_t)255; }

extern "C" void kernel_launch(void* const* d_in, const int* in_sizes, int n_in,
                              void* d_out, int out_size, void* d_ws, size_t ws_size,
                              hipStream_t stream) {
  const int*   Z    = (const int*)d_in[0];
  const float* disp = (const float*)d_in[1];
  const int*   nbr  = (const int*)d_in[2];
  const float* se   = (const float*)d_in[3];
  const float* Wt   = (const float*)d_in[4];
  const float* bt   = (const float*)d_in[5];
  const float* W1   = (const float*)d_in[6];
  const float* b1   = (const float*)d_in[7];
  const float* W2   = (const float*)d_in[8];
  const float* b2   = (const float*)d_in[9];
  float* out = (float*)d_out;

  const int A = in_sizes[0];
  const int P = in_sizes[1] / 3;

  char* ws = (char*)d_ws;
  size_t o = 0;
  unsigned short* G  = (unsigned short*)(ws + o); o += align256((size_t)P * 512 * 2);
  unsigned short* WT = (unsigned short*)(ws + o); o += align256((size_t)40960 * 2);
  int* counts = (int*)(ws + o); o += align256((size_t)A * 4);
  int* plist2 = (int*)(ws + o); o += align256((size_t)A * BUCKET * 4);
  (void)ws_size; (void)n_in; (void)out_size;

  const int nGemm = P / 64, nHist = P / 256;

  ktw<<<160, 256, 0, stream>>>(W1, W2, WT, counts, A);
  kA<<<nGemm + nHist, 256, 0, stream>>>(Z, nbr, disp, se, WT, b1, b2, G,
                                        counts, plist2, P);
  k3<<<(A + 3) / 4, 256, 0, stream>>>(G, Z, se, Wt, bt, counts, plist2, out, A);
}

// Round 10
// 121.049 us; speedup vs baseline: 1.0367x; 1.0367x over previous
//
#include <hip/hip_runtime.h>

#define DEVINL __device__ __forceinline__

typedef __attribute__((ext_vector_type(8))) short bf16x8;
typedef __attribute__((ext_vector_type(8))) unsigned short u16x8;
typedef __attribute__((ext_vector_type(4))) float f32x4;

constexpr int BUCKET = 96;  // max neighbors per atom (Poisson(16): P(>=96) ~ 0)

// ===========================================================================
// Compile-time math: even-parity triples (l1,l2,l3) and scalar A per triple.
// (T_p[(l1,l2,l3),m] = A * Y_{l3,m}(u_p); odd-parity A == 0.)  Verified R3/R4.
// ===========================================================================
constexpr int LMAX = 4;

struct Triples { int n; int l1[80], l2[80], l3[80]; };
constexpr Triples make_triples() {
  Triples T{}; T.n = 0;
  for (int a = 0; a <= LMAX; ++a)
    for (int b = 0; b <= LMAX; ++b)
      for (int c = 0; c <= LMAX; ++c) {
        int lo = a > b ? a - b : b - a;
        if (c < lo || c > a + b) continue;
        T.l1[T.n] = a; T.l2[T.n] = b; T.l3[T.n] = c; ++T.n;
      }
  return T;
}
constexpr Triples TRI = make_triples();
static_assert(TRI.n == 65, "triples");

struct ETriT { int n; signed char l1[48], l2[48], l3[48]; };
constexpr ETriT make_etri() {
  ETriT E{}; E.n = 0;
  for (int t = 0; t < TRI.n; ++t)
    if (((TRI.l1[t] + TRI.l2[t] + TRI.l3[t]) & 1) == 0) {
      E.l1[E.n] = (signed char)TRI.l1[t];
      E.l2[E.n] = (signed char)TRI.l2[t];
      E.l3[E.n] = (signed char)TRI.l3[t];
      ++E.n;
    }
  return E;
}
constexpr ETriT ETRI = make_etri();
static_assert(ETRI.n == 42, "even triples");

constexpr double FT[14] = {1., 1., 2., 6., 24., 120., 720., 5040., 40320.,
                           362880., 3628800., 39916800., 479001600., 6227020800.};

constexpr double csqrt(double x) {
  if (x <= 0.0) return 0.0;
  double y = 1.0;
  while (y * y < x) y *= 2.0;
  for (int i = 0; i < 30; ++i) y = 0.5 * (y + x / y);
  return y;
}

constexpr double cg_complex(int l1, int m1, int l2, int m2, int l3, int m3) {
  if (m1 + m2 != m3) return 0.0;
  double pref = csqrt((2.0 * l3 + 1.0) * FT[l1 + l2 - l3] * FT[l1 - l2 + l3] *
                      FT[-l1 + l2 + l3] / FT[l1 + l2 + l3 + 1]);
  pref *= csqrt(FT[l1 + m1] * FT[l1 - m1] * FT[l2 + m2] * FT[l2 - m2] *
                FT[l3 + m3] * FT[l3 - m3]);
  double s = 0.0;
  for (int k = 0; k <= l1 + l2 - l3; ++k) {
    int d3 = l1 - m1 - k, d4 = l2 + m2 - k, d5 = l3 - l2 + m1 + k, d6 = l3 - l1 - m2 + k;
    if (d3 < 0 || d4 < 0 || d5 < 0 || d6 < 0) continue;
    double den = FT[k] * FT[l1 + l2 - l3 - k] * FT[d3] * FT[d4] * FT[d5] * FT[d6];
    s += ((k & 1) ? -1.0 : 1.0) / den;
  }
  return pref * s;
}

struct CURow { int n; int m[2]; double re[2], im[2]; };
constexpr CURow cu_row(int l, int a) {
  CURow u{}; int ma = a - l;
  const double RS2 = 0.70710678118654752440;
  if (ma == 0) { u.n = 1; u.m[0] = 0; u.re[0] = 1.0; u.im[0] = 0.0; }
  else if (ma > 0) {
    u.n = 2;
    u.m[0] = ma;  u.re[0] = ((ma & 1) ? -RS2 : RS2); u.im[0] = 0.0;
    u.m[1] = -ma; u.re[1] = RS2;                     u.im[1] = 0.0;
  } else {
    int mm = -ma; u.n = 2;
    u.m[0] = -mm; u.re[0] = 0.0; u.im[0] = RS2;
    u.m[1] =  mm; u.re[1] = 0.0; u.im[1] = ((mm & 1) ? RS2 : -RS2);
  }
  return u;
}

constexpr double real_cg_entry(int l1, int a, int l2, int b, int l3, int c) {
  CURow u1 = cu_row(l1, a), u2 = cu_row(l2, b), u3 = cu_row(l3, c);
  double sre = 0.0, sim = 0.0;
  for (int x = 0; x < u1.n; ++x)
    for (int y = 0; y < u2.n; ++y)
      for (int z = 0; z < u3.n; ++z) {
        int m1 = u1.m[x], m2 = u2.m[y], m3 = u3.m[z];
        if (m1 + m2 != m3) continue;
        double cg = cg_complex(l1, m1, l2, m2, l3, m3);
        if (cg == 0.0) continue;
        double are = u1.re[x], aim = u1.im[x], bre = u2.re[y], bim = u2.im[y];
        double pre = are * bre - aim * bim, pim = are * bim + aim * bre;
        double cre = u3.re[z], cim = -u3.im[z];
        sre += (pre * cre - pim * cim) * cg;
        sim += (pre * cim + pim * cre) * cg;
      }
  return ((l1 + l2 + l3) & 1) ? sim : sre;
}

struct Y25D { double y[25]; };
constexpr Y25D csh25(double x, double y, double z) {
  Y25D Y{};
  double x2 = x * x, y2 = y * y, z2 = z * z;
  Y.y[0] = 0.28209479177387814;
  Y.y[1] = 0.4886025119029199 * y;
  Y.y[2] = 0.4886025119029199 * z;
  Y.y[3] = 0.4886025119029199 * x;
  Y.y[4] = 1.0925484305920792 * x * y;
  Y.y[5] = 1.0925484305920792 * y * z;
  Y.y[6] = 0.31539156525252005 * (3.0 * z2 - 1.0);
  Y.y[7] = 1.0925484305920792 * x * z;
  Y.y[8] = 0.5462742152960396 * (x2 - y2);
  Y.y[9] = 0.5900435899266435 * y * (3.0 * x2 - y2);
  Y.y[10] = 2.890611442640554 * x * y * z;
  Y.y[11] = 0.4570457994644658 * y * (5.0 * z2 - 1.0);
  Y.y[12] = 0.3731763325901154 * z * (5.0 * z2 - 3.0);
  Y.y[13] = 0.4570457994644658 * x * (5.0 * z2 - 1.0);
  Y.y[14] = 1.445305721320277 * z * (x2 - y2);
  Y.y[15] = 0.5900435899266435 * x * (x2 - 3.0 * y2);
  Y.y[16] = 2.5033429417967046 * x * y * (x2 - y2);
  Y.y[17] = 1.7701307697799304 * y * z * (3.0 * x2 - y2);
  Y.y[18] = 0.9461746957575601 * x * y * (7.0 * z2 - 1.0);
  Y.y[19] = 0.6690465435572892 * y * z * (7.0 * z2 - 3.0);
  Y.y[20] = 0.10578554691520431 * (35.0 * z2 * z2 - 30.0 * z2 + 3.0);
  Y.y[21] = 0.6690465435572892 * x * z * (7.0 * z2 - 3.0);
  Y.y[22] = 0.47308734787878004 * (x2 - y2) * (7.0 * z2 - 1.0);
  Y.y[23] = 1.7701307697799304 * x * z * (x2 - 3.0 * y2);
  Y.y[24] = 0.6258357354491761 * (x2 * x2 - 6.0 * x2 * y2 + y2 * y2);
  return Y;
}

constexpr double compute_A_even(int e) {
  int l1 = ETRI.l1[e], l2 = ETRI.l2[e], l3 = ETRI.l3[e];
  double ux = 0.437, uy = -0.602, uz = 0.668;
  double n = csqrt(ux * ux + uy * uy + uz * uz);
  Y25D Y = csh25(ux / n, uy / n, uz / n);
  int c0 = 2 * l3;
  double den = Y.y[l3 * l3 + c0];
  double num = 0.0;
  for (int a = 0; a < 2 * l1 + 1; ++a)
    for (int b = 0; b < 2 * l2 + 1; ++b) {
      double v = real_cg_entry(l1, a, l2, b, l3, c0);
      if (v != 0.0) num += v * Y.y[l1 * l1 + a] * Y.y[l2 * l2 + b];
    }
  return num / den;
}

template <int E> inline constexpr float A_of = (float)compute_A_even(E);
constexpr float AT42[42] = {
    A_of<0>,  A_of<1>,  A_of<2>,  A_of<3>,  A_of<4>,  A_of<5>,  A_of<6>,
    A_of<7>,  A_of<8>,  A_of<9>,  A_of<10>, A_of<11>, A_of<12>, A_of<13>,
    A_of<14>, A_of<15>, A_of<16>, A_of<17>, A_of<18>, A_of<19>, A_of<20>,
    A_of<21>, A_of<22>, A_of<23>, A_of<24>, A_of<25>, A_of<26>, A_of<27>,
    A_of<28>, A_of<29>, A_of<30>, A_of<31>, A_of<32>, A_of<33>, A_of<34>,
    A_of<35>, A_of<36>, A_of<37>, A_of<38>, A_of<39>, A_of<40>, A_of<41>};

// ===========================================================================
// Device helpers
// ===========================================================================
DEVINL unsigned short f2bf(float x) {
  unsigned u = __float_as_uint(x);
  u += 0x7FFFu + ((u >> 16) & 1u);
  return (unsigned short)(u >> 16);
}
DEVINL float bf2f(unsigned short b) { return __uint_as_float((unsigned)b << 16); }
DEVINL unsigned short f2h(float x) {
  return __builtin_bit_cast(unsigned short, (_Float16)x);
}
DEVINL float h2f(unsigned short h) {
  return (float)__builtin_bit_cast(_Float16, h);
}

DEVINL void sh25(float x, float y, float z, float* Y) {
  float x2 = x * x, y2 = y * y, z2 = z * z;
  Y[0] = 0.28209479177387814f;
  Y[1] = 0.4886025119029199f * y;
  Y[2] = 0.4886025119029199f * z;
  Y[3] = 0.4886025119029199f * x;
  Y[4] = 1.0925484305920792f * x * y;
  Y[5] = 1.0925484305920792f * y * z;
  Y[6] = 0.31539156525252005f * (3.0f * z2 - 1.0f);
  Y[7] = 1.0925484305920792f * x * z;
  Y[8] = 0.5462742152960396f * (x2 - y2);
  Y[9] = 0.5900435899266435f * y * (3.0f * x2 - y2);
  Y[10] = 2.890611442640554f * x * y * z;
  Y[11] = 0.4570457994644658f * y * (5.0f * z2 - 1.0f);
  Y[12] = 0.3731763325901154f * z * (5.0f * z2 - 3.0f);
  Y[13] = 0.4570457994644658f * x * (5.0f * z2 - 1.0f);
  Y[14] = 1.445305721320277f * z * (x2 - y2);
  Y[15] = 0.5900435899266435f * x * (x2 - 3.0f * y2);
  Y[16] = 2.5033429417967046f * x * y * (x2 - y2);
  Y[17] = 1.7701307697799304f * y * z * (3.0f * x2 - y2);
  Y[18] = 0.9461746957575601f * x * y * (7.0f * z2 - 1.0f);
  Y[19] = 0.6690465435572892f * y * z * (7.0f * z2 - 3.0f);
  Y[20] = 0.10578554691520431f * (35.0f * z2 * z2 - 30.0f * z2 + 3.0f);
  Y[21] = 0.6690465435572892f * x * z * (7.0f * z2 - 3.0f);
  Y[22] = 0.47308734787878004f * (x2 - y2) * (7.0f * z2 - 1.0f);
  Y[23] = 1.7701307697799304f * x * z * (x2 - 3.0f * y2);
  Y[24] = 0.6258357354491761f * (x2 * x2 - 6.0f * x2 * y2 + y2 * y2);
}

// ===========================================================================
// ktw: W -> bf16 WT [l*64+g][c]; block 159 also zeroes counts[]
// ===========================================================================
__global__ void ktw(const float* __restrict__ W1, const float* __restrict__ W2,
                    unsigned short* __restrict__ WT, int* __restrict__ counts, int A) {
  int idx = blockIdx.x * 256 + threadIdx.x;
  if (blockIdx.x == 159) {
    for (int i = threadIdx.x; i < A; i += 256) counts[i] = 0;
  }
  if (idx >= 40960) return;
  int c = idx & 63, g = (idx >> 6) & 63, l = idx >> 12;
  const float* W = (l < 5) ? (W1 + (size_t)l * 4096) : (W2 + (size_t)(l - 5) * 4096);
  WT[idx] = f2bf(W[c * 64 + g]);
}

// ===========================================================================
// kA (R8 shape): blocks [0, (P/128)*4): 128-pair x 16-g MFMA tile -> G.
//                blocks after: histogram + bucket scatter.
// G record (16 B per (p,f)): [5 bf16 G(l3) | 3 fp16 unit-dir].
// ===========================================================================
__global__ __launch_bounds__(256) void kA(const int* __restrict__ Z,
                                          const int* __restrict__ nbr,
                                          const float* __restrict__ disp,
                                          const float* __restrict__ se,
                                          const unsigned short* __restrict__ WT,
                                          const float* __restrict__ b1,
                                          const float* __restrict__ b2,
                                          unsigned short* __restrict__ G,
                                          int* __restrict__ counts,
                                          int* __restrict__ plist2,
                                          int P) {
  const int nGemm = (P / 128) * 4;
  const int t = threadIdx.x;

  if ((int)blockIdx.x >= nGemm) {
    int p = ((int)blockIdx.x - nGemm) * 256 + t;
    if (p < P) {
      int a = nbr[p];
      int rank = atomicAdd(&counts[a], 1);
      if (rank < BUCKET) plist2[a * BUCKET + rank] = p;
    }
    return;
  }

  __shared__ alignas(16) unsigned short rad[128 * 72];
  __shared__ unsigned short dird[128 * 3];
  const int bid = blockIdx.x;
  const int p0 = (bid >> 2) * 128;
  const int g0 = (bid & 3) * 16;

  {
    int pl = t >> 1, half = t & 1;
    int p = p0 + pl;
    int zj = Z[nbr[P + p]];
    float dx = disp[3 * p], dy = disp[3 * p + 1], dz = disp[3 * p + 2];
    float r = sqrtf(dx * dx + dy * dy + dz * dz + 1e-12f);
    float env = 0.5f * (__cosf(3.14159265358979f * fminf(r * 0.2f, 1.0f)) + 1.0f);
    const float delta = 5.0f / 63.0f;
    const float w = 0.5f / (delta * delta);
    if (half == 0) {
      float inv = 1.0f / r;
      dird[pl * 3 + 0] = f2h(dx * inv);
      dird[pl * 3 + 1] = f2h(dy * inv);
      dird[pl * 3 + 2] = f2h(dz * inv);
    }
    int c0 = half * 32;
    const float4* s4 = (const float4*)(se + (size_t)zj * 64 + c0);
    unsigned* radw = (unsigned*)rad;
#pragma unroll
    for (int i = 0; i < 8; ++i) {
      float4 s = s4[i];
      float d0 = r - (float)(c0 + 4 * i + 0) * delta;
      float d1 = r - (float)(c0 + 4 * i + 1) * delta;
      float d2 = r - (float)(c0 + 4 * i + 2) * delta;
      float d3 = r - (float)(c0 + 4 * i + 3) * delta;
      float v0 = __expf(-w * d0 * d0) * env * s.x;
      float v1 = __expf(-w * d1 * d1) * env * s.y;
      float v2 = __expf(-w * d2 * d2) * env * s.z;
      float v3 = __expf(-w * d3 * d3) * env * s.w;
      radw[pl * 36 + half * 16 + 2 * i] =
          (unsigned)f2bf(v0) | ((unsigned)f2bf(v1) << 16);
      radw[pl * 36 + half * 16 + 2 * i + 1] =
          (unsigned)f2bf(v2) | ((unsigned)f2bf(v3) << 16);
    }
  }
  __syncthreads();

  const int lane = t & 63, wv = t >> 6;
  const int n = lane & 15, quad = lane >> 4;
  const int g = g0 + n;
  const float invY0 = 3.5449077018110318f;

  bf16x8 B[10][2];
#pragma unroll
  for (int l = 0; l < 10; ++l)
#pragma unroll
    for (int kk = 0; kk < 2; ++kk)
      B[l][kk] = *(const bf16x8*)(WT + (((size_t)l * 64 + g) * 64 + kk * 32 + quad * 8));

  float bb1 = b1[g] * invY0, bb2 = b2[g] * invY0;

  const int m0 = wv * 32;
#pragma unroll
  for (int mt = 0; mt < 2; ++mt) {
    int row = m0 + mt * 16 + n;
    bf16x8 A0 = *(const bf16x8*)(rad + row * 72 + quad * 8);
    bf16x8 A1 = *(const bf16x8*)(rad + row * 72 + 32 + quad * 8);
    f32x4 C[10];
#pragma unroll
    for (int l = 0; l < 10; ++l) C[l] = (f32x4){0.f, 0.f, 0.f, 0.f};
#pragma unroll
    for (int l = 0; l < 10; ++l) {
      C[l] = __builtin_amdgcn_mfma_f32_16x16x32_bf16(A0, B[l][0], C[l], 0, 0, 0);
      C[l] = __builtin_amdgcn_mfma_f32_16x16x32_bf16(A1, B[l][1], C[l], 0, 0, 0);
    }
#pragma unroll
    for (int r = 0; r < 4; ++r) { C[0][r] += bb1; C[5][r] += bb2; }

    f32x4 Gac[5];
#pragma unroll
    for (int l = 0; l < 5; ++l) Gac[l] = (f32x4){0.f, 0.f, 0.f, 0.f};
#pragma unroll
    for (int l1 = 0; l1 < 5; ++l1)
#pragma unroll
      for (int l2 = 0; l2 < 5; ++l2) {
        f32x4 pr = C[l1] * C[5 + l2];
#pragma unroll
        for (int e = 0; e < 42; ++e)
          if ((int)ETRI.l1[e] == l1 && (int)ETRI.l2[e] == l2)
            Gac[(int)ETRI.l3[e]] += AT42[e] * pr;
      }

    const int lrow = m0 + mt * 16 + quad * 4;
#pragma unroll
    for (int r = 0; r < 4; ++r) {
      u16x8 pack;
      pack[0] = f2bf(Gac[0][r]); pack[1] = f2bf(Gac[1][r]);
      pack[2] = f2bf(Gac[2][r]); pack[3] = f2bf(Gac[3][r]);
      pack[4] = f2bf(Gac[4][r]);
      pack[5] = dird[(lrow + r) * 3 + 0];
      pack[6] = dird[(lrow + r) * 3 + 1];
      pack[7] = dird[(lrow + r) * 3 + 2];
      *(u16x8*)(G + (size_t)(p0 + lrow + r) * 512 + g * 8) = pack;
    }
  }
}

// ===========================================================================
// k3: 2 waves per atom (2 atoms per 256-block), lane = f.
// Bucket list register-resident (p via __shfl -> no address-chain memory dep);
// G loads prefetched depth 3; single LDS reduce between the atom's two waves.
// ===========================================================================
__global__ __launch_bounds__(256) void k3(const unsigned short* __restrict__ G,
                                          const int* __restrict__ Z,
                                          const float* __restrict__ se,
                                          const float* __restrict__ Wt,
                                          const float* __restrict__ bt,
                                          const int* __restrict__ counts,
                                          const int* __restrict__ plist2,
                                          float* __restrict__ out, int A) {
  __shared__ float red[2 * 1600];
  const int wv = threadIdx.x >> 6, f = threadIdx.x & 63;
  const int la = wv >> 1;   // local atom 0/1
  const int h = wv & 1;     // half of the pair list
  const int atom = blockIdx.x * 2 + la;
  const int atomc = atom < A ? atom : A - 1;

  float acc[25];
#pragma unroll
  for (int k = 0; k < 25; ++k) acc[k] = 0.f;

  int cnt = (atom < A) ? counts[atomc] : 0;
  cnt = cnt < BUCKET ? cnt : BUCKET;
  const int* bucket = plist2 + (size_t)atomc * BUCKET;
  // register-resident bucket: lane i holds bucket[i]; second reg holds 64..95
  int rb0 = bucket[f];
  int rb1 = bucket[64 + (f & 31)];

  // this wave handles q = h, h+2, h+4, ...  (nq iterations)
  int nq = (cnt > h) ? ((cnt - h + 1) >> 1) : 0;

#define GETP(i)                                                     \
  ({ int q_ = h + 2 * (i);                                          \
     (q_ < 64) ? __shfl(rb0, q_) : __shfl(rb1, q_ - 64); })
#define LDG(p_) (*(const u16x8*)(G + (size_t)(p_)*512 + f * 8))

  u16x8 v0, v1, v2;
  if (nq > 0) v0 = LDG(GETP(0));
  if (nq > 1) v1 = LDG(GETP(1));
  if (nq > 2) v2 = LDG(GETP(2));

#define BODY(gc)                                                    \
  {                                                                 \
    float g0 = bf2f(gc[0]), g1 = bf2f(gc[1]), g2 = bf2f(gc[2]);     \
    float g3 = bf2f(gc[3]), g4 = bf2f(gc[4]);                       \
    float ux = h2f(gc[5]), uy = h2f(gc[6]), uz = h2f(gc[7]);        \
    float Y[25];                                                    \
    sh25(ux, uy, uz, Y);                                            \
    acc[0] = fmaf(Y[0], g0, acc[0]);                                \
    _Pragma("unroll") for (int k = 1; k < 4; ++k)                   \
        acc[k] = fmaf(Y[k], g1, acc[k]);                            \
    _Pragma("unroll") for (int k = 4; k < 9; ++k)                   \
        acc[k] = fmaf(Y[k], g2, acc[k]);                            \
    _Pragma("unroll") for (int k = 9; k < 16; ++k)                  \
        acc[k] = fmaf(Y[k], g3, acc[k]);                            \
    _Pragma("unroll") for (int k = 16; k < 25; ++k)                 \
        acc[k] = fmaf(Y[k], g4, acc[k]);                            \
  }

  int i = 0;
  while (i < nq) {
    BODY(v0);
    if (i + 3 < nq) v0 = LDG(GETP(i + 3));
    ++i;
    if (i >= nq) break;
    BODY(v1);
    if (i + 3 < nq) v1 = LDG(GETP(i + 3));
    ++i;
    if (i >= nq) break;
    BODY(v2);
    if (i + 3 < nq) v2 = LDG(GETP(i + 3));
    ++i;
  }
#undef BODY
#undef LDG
#undef GETP

  if (h == 1) {
#pragma unroll
    for (int k = 0; k < 25; ++k) red[la * 1600 + k * 64 + f] = acc[k];
  }
  __syncthreads();
  if (h == 0 && atom < A) {
#pragma unroll
    for (int k = 0; k < 25; ++k) acc[k] += red[la * 1600 + k * 64 + f];
    int z = Z[atom];
    float e = bt[f];
    for (int c = 0; c < 64; ++c)
      e = fmaf(se[(size_t)z * 64 + c], Wt[(size_t)c * 64 + f], e);
#pragma unroll
    for (int k = 0; k < 25; ++k)
      out[(size_t)atom * 1600 + (size_t)k * 64 + f] = fmaf(acc[k], e, (k == 0) ? e : 0.f);
  }
}

// ===========================================================================
// Launch: 3 dispatches
// ===========================================================================
static inline size_t align256(size_t x) { return (x + 255) & ~(size_t)255; }

extern "C" void kernel_launch(void* const* d_in, const int* in_sizes, int n_in,
                              void* d_out, int out_size, void* d_ws, size_t ws_size,
                              hipStream_t stream) {
  const int*   Z    = (const int*)d_in[0];
  const float* disp = (const float*)d_in[1];
  const int*   nbr  = (const int*)d_in[2];
  const float* se   = (const float*)d_in[3];
  const float* Wt   = (const float*)d_in[4];
  const float* bt   = (const float*)d_in[5];
  const float* W1   = (const float*)d_in[6];
  const float* b1   = (const float*)d_in[7];
  const float* W2   = (const float*)d_in[8];
  const float* b2   = (const float*)d_in[9];
  float* out = (float*)d_out;

  const int A = in_sizes[0];
  const int P = in_sizes[1] / 3;

  char* ws = (char*)d_ws;
  size_t o = 0;
  unsigned short* G  = (unsigned short*)(ws + o); o += align256((size_t)P * 512 * 2);
  unsigned short* WT = (unsigned short*)(ws + o); o += align256((size_t)40960 * 2);
  int* counts = (int*)(ws + o); o += align256((size_t)A * 4);
  int* plist2 = (int*)(ws + o); o += align256((size_t)A * BUCKET * 4);
  (void)ws_size; (void)n_in; (void)out_size;

  const int nGemm = (P / 128) * 4, nHist = P / 256;

  ktw<<<160, 256, 0, stream>>>(W1, W2, WT, counts, A);
  kA<<<nGemm + nHist, 256, 0, stream>>>(Z, nbr, disp, se, WT, b1, b2, G,
                                        counts, plist2, P);
  k3<<<(A + 1) / 2, 256, 0, stream>>>(G, Z, se, Wt, bt, counts, plist2, out, A);
}

// Round 11
// 117.719 us; speedup vs baseline: 1.0661x; 1.0283x over previous
//
#include <hip/hip_runtime.h>

#define DEVINL __device__ __forceinline__

typedef __attribute__((ext_vector_type(8))) short bf16x8;
typedef __attribute__((ext_vector_type(8))) unsigned short u16x8;
typedef __attribute__((ext_vector_type(4))) float f32x4;

constexpr int BUCKET = 96;  // max neighbors per atom (Poisson(16): P(>=96) ~ 0)

// ===========================================================================
// Compile-time math: even-parity triples (l1,l2,l3) and scalar A per triple.
// (T_p[(l1,l2,l3),m] = A * Y_{l3,m}(u_p); odd-parity A == 0.)  Verified R3/R4.
// ===========================================================================
constexpr int LMAX = 4;

struct Triples { int n; int l1[80], l2[80], l3[80]; };
constexpr Triples make_triples() {
  Triples T{}; T.n = 0;
  for (int a = 0; a <= LMAX; ++a)
    for (int b = 0; b <= LMAX; ++b)
      for (int c = 0; c <= LMAX; ++c) {
        int lo = a > b ? a - b : b - a;
        if (c < lo || c > a + b) continue;
        T.l1[T.n] = a; T.l2[T.n] = b; T.l3[T.n] = c; ++T.n;
      }
  return T;
}
constexpr Triples TRI = make_triples();
static_assert(TRI.n == 65, "triples");

struct ETriT { int n; signed char l1[48], l2[48], l3[48]; };
constexpr ETriT make_etri() {
  ETriT E{}; E.n = 0;
  for (int t = 0; t < TRI.n; ++t)
    if (((TRI.l1[t] + TRI.l2[t] + TRI.l3[t]) & 1) == 0) {
      E.l1[E.n] = (signed char)TRI.l1[t];
      E.l2[E.n] = (signed char)TRI.l2[t];
      E.l3[E.n] = (signed char)TRI.l3[t];
      ++E.n;
    }
  return E;
}
constexpr ETriT ETRI = make_etri();
static_assert(ETRI.n == 42, "even triples");

constexpr double FT[14] = {1., 1., 2., 6., 24., 120., 720., 5040., 40320.,
                           362880., 3628800., 39916800., 479001600., 6227020800.};

constexpr double csqrt(double x) {
  if (x <= 0.0) return 0.0;
  double y = 1.0;
  while (y * y < x) y *= 2.0;
  for (int i = 0; i < 30; ++i) y = 0.5 * (y + x / y);
  return y;
}

constexpr double cg_complex(int l1, int m1, int l2, int m2, int l3, int m3) {
  if (m1 + m2 != m3) return 0.0;
  double pref = csqrt((2.0 * l3 + 1.0) * FT[l1 + l2 - l3] * FT[l1 - l2 + l3] *
                      FT[-l1 + l2 + l3] / FT[l1 + l2 + l3 + 1]);
  pref *= csqrt(FT[l1 + m1] * FT[l1 - m1] * FT[l2 + m2] * FT[l2 - m2] *
                FT[l3 + m3] * FT[l3 - m3]);
  double s = 0.0;
  for (int k = 0; k <= l1 + l2 - l3; ++k) {
    int d3 = l1 - m1 - k, d4 = l2 + m2 - k, d5 = l3 - l2 + m1 + k, d6 = l3 - l1 - m2 + k;
    if (d3 < 0 || d4 < 0 || d5 < 0 || d6 < 0) continue;
    double den = FT[k] * FT[l1 + l2 - l3 - k] * FT[d3] * FT[d4] * FT[d5] * FT[d6];
    s += ((k & 1) ? -1.0 : 1.0) / den;
  }
  return pref * s;
}

struct CURow { int n; int m[2]; double re[2], im[2]; };
constexpr CURow cu_row(int l, int a) {
  CURow u{}; int ma = a - l;
  const double RS2 = 0.70710678118654752440;
  if (ma == 0) { u.n = 1; u.m[0] = 0; u.re[0] = 1.0; u.im[0] = 0.0; }
  else if (ma > 0) {
    u.n = 2;
    u.m[0] = ma;  u.re[0] = ((ma & 1) ? -RS2 : RS2); u.im[0] = 0.0;
    u.m[1] = -ma; u.re[1] = RS2;                     u.im[1] = 0.0;
  } else {
    int mm = -ma; u.n = 2;
    u.m[0] = -mm; u.re[0] = 0.0; u.im[0] = RS2;
    u.m[1] =  mm; u.re[1] = 0.0; u.im[1] = ((mm & 1) ? RS2 : -RS2);
  }
  return u;
}

constexpr double real_cg_entry(int l1, int a, int l2, int b, int l3, int c) {
  CURow u1 = cu_row(l1, a), u2 = cu_row(l2, b), u3 = cu_row(l3, c);
  double sre = 0.0, sim = 0.0;
  for (int x = 0; x < u1.n; ++x)
    for (int y = 0; y < u2.n; ++y)
      for (int z = 0; z < u3.n; ++z) {
        int m1 = u1.m[x], m2 = u2.m[y], m3 = u3.m[z];
        if (m1 + m2 != m3) continue;
        double cg = cg_complex(l1, m1, l2, m2, l3, m3);
        if (cg == 0.0) continue;
        double are = u1.re[x], aim = u1.im[x], bre = u2.re[y], bim = u2.im[y];
        double pre = are * bre - aim * bim, pim = are * bim + aim * bre;
        double cre = u3.re[z], cim = -u3.im[z];
        sre += (pre * cre - pim * cim) * cg;
        sim += (pre * cim + pim * cre) * cg;
      }
  return ((l1 + l2 + l3) & 1) ? sim : sre;
}

struct Y25D { double y[25]; };
constexpr Y25D csh25(double x, double y, double z) {
  Y25D Y{};
  double x2 = x * x, y2 = y * y, z2 = z * z;
  Y.y[0] = 0.28209479177387814;
  Y.y[1] = 0.4886025119029199 * y;
  Y.y[2] = 0.4886025119029199 * z;
  Y.y[3] = 0.4886025119029199 * x;
  Y.y[4] = 1.0925484305920792 * x * y;
  Y.y[5] = 1.0925484305920792 * y * z;
  Y.y[6] = 0.31539156525252005 * (3.0 * z2 - 1.0);
  Y.y[7] = 1.0925484305920792 * x * z;
  Y.y[8] = 0.5462742152960396 * (x2 - y2);
  Y.y[9] = 0.5900435899266435 * y * (3.0 * x2 - y2);
  Y.y[10] = 2.890611442640554 * x * y * z;
  Y.y[11] = 0.4570457994644658 * y * (5.0 * z2 - 1.0);
  Y.y[12] = 0.3731763325901154 * z * (5.0 * z2 - 3.0);
  Y.y[13] = 0.4570457994644658 * x * (5.0 * z2 - 1.0);
  Y.y[14] = 1.445305721320277 * z * (x2 - y2);
  Y.y[15] = 0.5900435899266435 * x * (x2 - 3.0 * y2);
  Y.y[16] = 2.5033429417967046 * x * y * (x2 - y2);
  Y.y[17] = 1.7701307697799304 * y * z * (3.0 * x2 - y2);
  Y.y[18] = 0.9461746957575601 * x * y * (7.0 * z2 - 1.0);
  Y.y[19] = 0.6690465435572892 * y * z * (7.0 * z2 - 3.0);
  Y.y[20] = 0.10578554691520431 * (35.0 * z2 * z2 - 30.0 * z2 + 3.0);
  Y.y[21] = 0.6690465435572892 * x * z * (7.0 * z2 - 3.0);
  Y.y[22] = 0.47308734787878004 * (x2 - y2) * (7.0 * z2 - 1.0);
  Y.y[23] = 1.7701307697799304 * x * z * (x2 - 3.0 * y2);
  Y.y[24] = 0.6258357354491761 * (x2 * x2 - 6.0 * x2 * y2 + y2 * y2);
  return Y;
}

constexpr double compute_A_even(int e) {
  int l1 = ETRI.l1[e], l2 = ETRI.l2[e], l3 = ETRI.l3[e];
  double ux = 0.437, uy = -0.602, uz = 0.668;
  double n = csqrt(ux * ux + uy * uy + uz * uz);
  Y25D Y = csh25(ux / n, uy / n, uz / n);
  int c0 = 2 * l3;
  double den = Y.y[l3 * l3 + c0];
  double num = 0.0;
  for (int a = 0; a < 2 * l1 + 1; ++a)
    for (int b = 0; b < 2 * l2 + 1; ++b) {
      double v = real_cg_entry(l1, a, l2, b, l3, c0);
      if (v != 0.0) num += v * Y.y[l1 * l1 + a] * Y.y[l2 * l2 + b];
    }
  return num / den;
}

template <int E> inline constexpr float A_of = (float)compute_A_even(E);
constexpr float AT42[42] = {
    A_of<0>,  A_of<1>,  A_of<2>,  A_of<3>,  A_of<4>,  A_of<5>,  A_of<6>,
    A_of<7>,  A_of<8>,  A_of<9>,  A_of<10>, A_of<11>, A_of<12>, A_of<13>,
    A_of<14>, A_of<15>, A_of<16>, A_of<17>, A_of<18>, A_of<19>, A_of<20>,
    A_of<21>, A_of<22>, A_of<23>, A_of<24>, A_of<25>, A_of<26>, A_of<27>,
    A_of<28>, A_of<29>, A_of<30>, A_of<31>, A_of<32>, A_of<33>, A_of<34>,
    A_of<35>, A_of<36>, A_of<37>, A_of<38>, A_of<39>, A_of<40>, A_of<41>};

// ===========================================================================
// Device helpers
// ===========================================================================
DEVINL unsigned short f2bf(float x) {
  unsigned u = __float_as_uint(x);
  u += 0x7FFFu + ((u >> 16) & 1u);
  return (unsigned short)(u >> 16);
}
DEVINL float bf2f(unsigned short b) { return __uint_as_float((unsigned)b << 16); }
DEVINL unsigned short f2h(float x) {
  return __builtin_bit_cast(unsigned short, (_Float16)x);
}
DEVINL float h2f(unsigned short h) {
  return (float)__builtin_bit_cast(_Float16, h);
}
DEVINL void up2(unsigned d, float& a, float& b) {
  a = h2f((unsigned short)(d & 0xFFFFu));
  b = h2f((unsigned short)(d >> 16));
}

DEVINL void sh25(float x, float y, float z, float* Y) {
  float x2 = x * x, y2 = y * y, z2 = z * z;
  Y[0] = 0.28209479177387814f;
  Y[1] = 0.4886025119029199f * y;
  Y[2] = 0.4886025119029199f * z;
  Y[3] = 0.4886025119029199f * x;
  Y[4] = 1.0925484305920792f * x * y;
  Y[5] = 1.0925484305920792f * y * z;
  Y[6] = 0.31539156525252005f * (3.0f * z2 - 1.0f);
  Y[7] = 1.0925484305920792f * x * z;
  Y[8] = 0.5462742152960396f * (x2 - y2);
  Y[9] = 0.5900435899266435f * y * (3.0f * x2 - y2);
  Y[10] = 2.890611442640554f * x * y * z;
  Y[11] = 0.4570457994644658f * y * (5.0f * z2 - 1.0f);
  Y[12] = 0.3731763325901154f * z * (5.0f * z2 - 3.0f);
  Y[13] = 0.4570457994644658f * x * (5.0f * z2 - 1.0f);
  Y[14] = 1.445305721320277f * z * (x2 - y2);
  Y[15] = 0.5900435899266435f * x * (x2 - 3.0f * y2);
  Y[16] = 2.5033429417967046f * x * y * (x2 - y2);
  Y[17] = 1.7701307697799304f * y * z * (3.0f * x2 - y2);
  Y[18] = 0.9461746957575601f * x * y * (7.0f * z2 - 1.0f);
  Y[19] = 0.6690465435572892f * y * z * (7.0f * z2 - 3.0f);
  Y[20] = 0.10578554691520431f * (35.0f * z2 * z2 - 30.0f * z2 + 3.0f);
  Y[21] = 0.6690465435572892f * x * z * (7.0f * z2 - 3.0f);
  Y[22] = 0.47308734787878004f * (x2 - y2) * (7.0f * z2 - 1.0f);
  Y[23] = 1.7701307697799304f * x * z * (x2 - 3.0f * y2);
  Y[24] = 0.6258357354491761f * (x2 * x2 - 6.0f * x2 * y2 + y2 * y2);
}

// ===========================================================================
// ktw: W -> bf16 WT [l*64+g][c]; block 159 also zeroes counts[]
// ===========================================================================
__global__ void ktw(const float* __restrict__ W1, const float* __restrict__ W2,
                    unsigned short* __restrict__ WT, int* __restrict__ counts, int A) {
  int idx = blockIdx.x * 256 + threadIdx.x;
  if (blockIdx.x == 159) {
    for (int i = threadIdx.x; i < A; i += 256) counts[i] = 0;
  }
  if (idx >= 40960) return;
  int c = idx & 63, g = (idx >> 6) & 63, l = idx >> 12;
  const float* W = (l < 5) ? (W1 + (size_t)l * 4096) : (W2 + (size_t)(l - 5) * 4096);
  WT[idx] = f2bf(W[c * 64 + g]);
}

// ===========================================================================
// kA: blocks [0, (P/128)*4): 128-pair x 16-g MFMA tile -> G; staging also
//     computes per-pair Y[25] (fp32 sh25, stored fp16) into Ybuf ONCE.
//     blocks after: histogram + bucket scatter.
// G record (16 B per (p,f)): [5 bf16 G(l3) | 3 pad].
// Ybuf record (64 B per pair): 25 fp16 Y + pad.
// ===========================================================================
__global__ __launch_bounds__(256) void kA(const int* __restrict__ Z,
                                          const int* __restrict__ nbr,
                                          const float* __restrict__ disp,
                                          const float* __restrict__ se,
                                          const unsigned short* __restrict__ WT,
                                          const float* __restrict__ b1,
                                          const float* __restrict__ b2,
                                          unsigned short* __restrict__ G,
                                          unsigned short* __restrict__ Ybuf,
                                          int* __restrict__ counts,
                                          int* __restrict__ plist2,
                                          int P) {
  const int nGemm = (P / 128) * 4;
  const int t = threadIdx.x;

  if ((int)blockIdx.x >= nGemm) {
    int p = ((int)blockIdx.x - nGemm) * 256 + t;
    if (p < P) {
      int a = nbr[p];
      int rank = atomicAdd(&counts[a], 1);
      if (rank < BUCKET) plist2[a * BUCKET + rank] = p;
    }
    return;
  }

  __shared__ alignas(16) unsigned short rad[128 * 72];
  const int bid = blockIdx.x;
  const int p0 = (bid >> 2) * 128;
  const int g0 = (bid & 3) * 16;
  const bool firstg = (bid & 3) == 0;  // only one g-block writes Ybuf per pair

  {
    int pl = t >> 1, half = t & 1;
    int p = p0 + pl;
    int zj = Z[nbr[P + p]];
    float dx = disp[3 * p], dy = disp[3 * p + 1], dz = disp[3 * p + 2];
    float r = sqrtf(dx * dx + dy * dy + dz * dz + 1e-12f);
    float env = 0.5f * (__cosf(3.14159265358979f * fminf(r * 0.2f, 1.0f)) + 1.0f);
    const float delta = 5.0f / 63.0f;
    const float w = 0.5f / (delta * delta);
    if (half == 0 && firstg) {
      float inv = 1.0f / r;
      float Yv[25];
      sh25(dx * inv, dy * inv, dz * inv, Yv);
      unsigned yw[13];
#pragma unroll
      for (int j = 0; j < 12; ++j)
        yw[j] = (unsigned)f2h(Yv[2 * j]) | ((unsigned)f2h(Yv[2 * j + 1]) << 16);
      yw[12] = (unsigned)f2h(Yv[24]);
      uint4* yp = (uint4*)(Ybuf + (size_t)p * 32);
      yp[0] = make_uint4(yw[0], yw[1], yw[2], yw[3]);
      yp[1] = make_uint4(yw[4], yw[5], yw[6], yw[7]);
      yp[2] = make_uint4(yw[8], yw[9], yw[10], yw[11]);
      ((unsigned*)(Ybuf + (size_t)p * 32))[12] = yw[12];
    }
    int c0 = half * 32;
    const float4* s4 = (const float4*)(se + (size_t)zj * 64 + c0);
    unsigned* radw = (unsigned*)rad;
#pragma unroll
    for (int i = 0; i < 8; ++i) {
      float4 s = s4[i];
      float d0 = r - (float)(c0 + 4 * i + 0) * delta;
      float d1 = r - (float)(c0 + 4 * i + 1) * delta;
      float d2 = r - (float)(c0 + 4 * i + 2) * delta;
      float d3 = r - (float)(c0 + 4 * i + 3) * delta;
      float v0 = __expf(-w * d0 * d0) * env * s.x;
      float v1 = __expf(-w * d1 * d1) * env * s.y;
      float v2 = __expf(-w * d2 * d2) * env * s.z;
      float v3 = __expf(-w * d3 * d3) * env * s.w;
      radw[pl * 36 + half * 16 + 2 * i] =
          (unsigned)f2bf(v0) | ((unsigned)f2bf(v1) << 16);
      radw[pl * 36 + half * 16 + 2 * i + 1] =
          (unsigned)f2bf(v2) | ((unsigned)f2bf(v3) << 16);
    }
  }
  __syncthreads();

  const int lane = t & 63, wv = t >> 6;
  const int n = lane & 15, quad = lane >> 4;
  const int g = g0 + n;
  const float invY0 = 3.5449077018110318f;

  bf16x8 B[10][2];
#pragma unroll
  for (int l = 0; l < 10; ++l)
#pragma unroll
    for (int kk = 0; kk < 2; ++kk)
      B[l][kk] = *(const bf16x8*)(WT + (((size_t)l * 64 + g) * 64 + kk * 32 + quad * 8));

  float bb1 = b1[g] * invY0, bb2 = b2[g] * invY0;

  const int m0 = wv * 32;
#pragma unroll
  for (int mt = 0; mt < 2; ++mt) {
    int row = m0 + mt * 16 + n;
    bf16x8 A0 = *(const bf16x8*)(rad + row * 72 + quad * 8);
    bf16x8 A1 = *(const bf16x8*)(rad + row * 72 + 32 + quad * 8);
    f32x4 C[10];
#pragma unroll
    for (int l = 0; l < 10; ++l) C[l] = (f32x4){0.f, 0.f, 0.f, 0.f};
#pragma unroll
    for (int l = 0; l < 10; ++l) {
      C[l] = __builtin_amdgcn_mfma_f32_16x16x32_bf16(A0, B[l][0], C[l], 0, 0, 0);
      C[l] = __builtin_amdgcn_mfma_f32_16x16x32_bf16(A1, B[l][1], C[l], 0, 0, 0);
    }
#pragma unroll
    for (int r = 0; r < 4; ++r) { C[0][r] += bb1; C[5][r] += bb2; }

    f32x4 Gac[5];
#pragma unroll
    for (int l = 0; l < 5; ++l) Gac[l] = (f32x4){0.f, 0.f, 0.f, 0.f};
#pragma unroll
    for (int l1 = 0; l1 < 5; ++l1)
#pragma unroll
      for (int l2 = 0; l2 < 5; ++l2) {
        f32x4 pr = C[l1] * C[5 + l2];
#pragma unroll
        for (int e = 0; e < 42; ++e)
          if ((int)ETRI.l1[e] == l1 && (int)ETRI.l2[e] == l2)
            Gac[(int)ETRI.l3[e]] += AT42[e] * pr;
      }

    const int lrow = m0 + mt * 16 + quad * 4;
#pragma unroll
    for (int r = 0; r < 4; ++r) {
      u16x8 pack;
      pack[0] = f2bf(Gac[0][r]); pack[1] = f2bf(Gac[1][r]);
      pack[2] = f2bf(Gac[2][r]); pack[3] = f2bf(Gac[3][r]);
      pack[4] = f2bf(Gac[4][r]);
      pack[5] = 0; pack[6] = 0; pack[7] = 0;
      *(u16x8*)(G + (size_t)(p0 + lrow + r) * 512 + g * 8) = pack;
    }
  }
}

// ===========================================================================
// k3: 2 waves per atom (2 atoms per 256-block), lane = f.
// Bucket register-resident (p via shfl+readfirstlane); per pair ONE per-lane
// dwordx4 (G) + wave-broadcast Y[25] fp16 loads; depth-2 rotated prefetch.
// No per-lane sh25. Single LDS reduce; fused emb epilogue.
// ===========================================================================
struct K3Stage { u16x8 g; uint4 y0, y1, y2; unsigned y3; };

DEVINL K3Stage k3_load(const unsigned short* __restrict__ G,
                       const unsigned short* __restrict__ Ybuf, int p, int f) {
  K3Stage s;
  s.g = *(const u16x8*)(G + (size_t)p * 512 + f * 8);
  const uint4* yp = (const uint4*)(Ybuf + (size_t)p * 32);
  s.y0 = yp[0]; s.y1 = yp[1]; s.y2 = yp[2];
  s.y3 = ((const unsigned*)(Ybuf + (size_t)p * 32))[12];
  return s;
}

__global__ __launch_bounds__(256) void k3(const unsigned short* __restrict__ G,
                                          const unsigned short* __restrict__ Ybuf,
                                          const int* __restrict__ Z,
                                          const float* __restrict__ se,
                                          const float* __restrict__ Wt,
                                          const float* __restrict__ bt,
                                          const int* __restrict__ counts,
                                          const int* __restrict__ plist2,
                                          float* __restrict__ out, int A) {
  __shared__ float red[2 * 1600];
  const int wv = threadIdx.x >> 6, f = threadIdx.x & 63;
  const int la = wv >> 1;   // local atom 0/1
  const int h = wv & 1;     // half of the pair list
  const int atom = blockIdx.x * 2 + la;
  const int atomc = atom < A ? atom : A - 1;

  float acc[25];
#pragma unroll
  for (int k = 0; k < 25; ++k) acc[k] = 0.f;

  int cnt = (atom < A) ? counts[atomc] : 0;
  cnt = cnt < BUCKET ? cnt : BUCKET;
  const int* bucket = plist2 + (size_t)atomc * BUCKET;
  int rb0 = bucket[f];
  int rb1 = bucket[64 + (f & 31)];

  int nq = (cnt > h) ? ((cnt - h + 1) >> 1) : 0;

#define GETP(i)                                                           \
  ({ int q_ = h + 2 * (i);                                                \
     int v_ = (q_ < 64) ? __shfl(rb0, q_) : __shfl(rb1, q_ - 64);         \
     __builtin_amdgcn_readfirstlane(v_); })

  K3Stage sA, sB;
  if (nq > 0) sA = k3_load(G, Ybuf, GETP(0), f);
  if (nq > 1) sB = k3_load(G, Ybuf, GETP(1), f);

#define BODY(s)                                                           \
  {                                                                       \
    float Yv[25];                                                         \
    up2(s.y0.x, Yv[0], Yv[1]);   up2(s.y0.y, Yv[2], Yv[3]);               \
    up2(s.y0.z, Yv[4], Yv[5]);   up2(s.y0.w, Yv[6], Yv[7]);               \
    up2(s.y1.x, Yv[8], Yv[9]);   up2(s.y1.y, Yv[10], Yv[11]);             \
    up2(s.y1.z, Yv[12], Yv[13]); up2(s.y1.w, Yv[14], Yv[15]);             \
    up2(s.y2.x, Yv[16], Yv[17]); up2(s.y2.y, Yv[18], Yv[19]);             \
    up2(s.y2.z, Yv[20], Yv[21]); up2(s.y2.w, Yv[22], Yv[23]);             \
    Yv[24] = h2f((unsigned short)(s.y3 & 0xFFFFu));                       \
    float g0 = bf2f(s.g[0]), g1 = bf2f(s.g[1]), g2 = bf2f(s.g[2]);        \
    float g3 = bf2f(s.g[3]), g4 = bf2f(s.g[4]);                           \
    acc[0] = fmaf(Yv[0], g0, acc[0]);                                     \
    _Pragma("unroll") for (int k = 1; k < 4; ++k)                         \
        acc[k] = fmaf(Yv[k], g1, acc[k]);                                 \
    _Pragma("unroll") for (int k = 4; k < 9; ++k)                         \
        acc[k] = fmaf(Yv[k], g2, acc[k]);                                 \
    _Pragma("unroll") for (int k = 9; k < 16; ++k)                        \
        acc[k] = fmaf(Yv[k], g3, acc[k]);                                 \
    _Pragma("unroll") for (int k = 16; k < 25; ++k)                       \
        acc[k] = fmaf(Yv[k], g4, acc[k]);                                 \
  }

  int i = 0;
  while (i < nq) {
    BODY(sA);
    if (i + 2 < nq) sA = k3_load(G, Ybuf, GETP(i + 2), f);
    ++i;
    if (i >= nq) break;
    BODY(sB);
    if (i + 2 < nq) sB = k3_load(G, Ybuf, GETP(i + 2), f);
    ++i;
  }
#undef BODY
#undef GETP

  if (h == 1) {
#pragma unroll
    for (int k = 0; k < 25; ++k) red[la * 1600 + k * 64 + f] = acc[k];
  }
  __syncthreads();
  if (h == 0 && atom < A) {
#pragma unroll
    for (int k = 0; k < 25; ++k) acc[k] += red[la * 1600 + k * 64 + f];
    int z = Z[atom];
    float e = bt[f];
    for (int c = 0; c < 64; ++c)
      e = fmaf(se[(size_t)z * 64 + c], Wt[(size_t)c * 64 + f], e);
#pragma unroll
    for (int k = 0; k < 25; ++k)
      out[(size_t)atom * 1600 + (size_t)k * 64 + f] = fmaf(acc[k], e, (k == 0) ? e : 0.f);
  }
}

// ===========================================================================
// Launch: 3 dispatches
// ===========================================================================
static inline size_t align256(size_t x) { return (x + 255) & ~(size_t)255; }

extern "C" void kernel_launch(void* const* d_in, const int* in_sizes, int n_in,
                              void* d_out, int out_size, void* d_ws, size_t ws_size,
                              hipStream_t stream) {
  const int*   Z    = (const int*)d_in[0];
  const float* disp = (const float*)d_in[1];
  const int*   nbr  = (const int*)d_in[2];
  const float* se   = (const float*)d_in[3];
  const float* Wt   = (const float*)d_in[4];
  const float* bt   = (const float*)d_in[5];
  const float* W1   = (const float*)d_in[6];
  const float* b1   = (const float*)d_in[7];
  const float* W2   = (const float*)d_in[8];
  const float* b2   = (const float*)d_in[9];
  float* out = (float*)d_out;

  const int A = in_sizes[0];
  const int P = in_sizes[1] / 3;

  char* ws = (char*)d_ws;
  size_t o = 0;
  unsigned short* G    = (unsigned short*)(ws + o); o += align256((size_t)P * 512 * 2);
  unsigned short* Ybuf = (unsigned short*)(ws + o); o += align256((size_t)P * 32 * 2);
  unsigned short* WT   = (unsigned short*)(ws + o); o += align256((size_t)40960 * 2);
  int* counts = (int*)(ws + o); o += align256((size_t)A * 4);
  int* plist2 = (int*)(ws + o); o += align256((size_t)A * BUCKET * 4);
  (void)ws_size; (void)n_in; (void)out_size;

  const int nGemm = (P / 128) * 4, nHist = P / 256;

  ktw<<<160, 256, 0, stream>>>(W1, W2, WT, counts, A);
  kA<<<nGemm + nHist, 256, 0, stream>>>(Z, nbr, disp, se, WT, b1, b2, G, Ybuf,
                                        counts, plist2, P);
  k3<<<(A + 1) / 2, 256, 0, stream>>>(G, Ybuf, Z, se, Wt, bt, counts, plist2,
                                      out, A);
}